// Round 2
// baseline (351.097 us; speedup 1.0000x reference)
//
#include <hip/hip_runtime.h>
#include <hip/hip_bf16.h>

#define N 8192
#define D 64

typedef __attribute__((ext_vector_type(8))) short bf16x8;
typedef __attribute__((ext_vector_type(4))) float f32x4;

__device__ inline unsigned short f2b(float f) {
    __hip_bfloat16 h = __float2bfloat16(f);
    return __builtin_bit_cast(unsigned short, h);
}

// Kernel 1: X (fp32) -> Xb (bf16); sq[i] = ||x_i||^2; per-block column partials Vp.
// 512 blocks x 256 threads, each thread one float4 (4 elems). 16 threads = 1 row.
__global__ __launch_bounds__(256) void gk_prep(const float4* __restrict__ X4,
                                               ushort4* __restrict__ Xb4,
                                               float* __restrict__ sq,
                                               float4* __restrict__ Vp4) {
    __shared__ float4 sm[256];
    const int tid = threadIdx.x;
    const int g = blockIdx.x * 256 + tid;   // float4 index
    float4 v = X4[g];
    ushort4 b;
    b.x = f2b(v.x); b.y = f2b(v.y); b.z = f2b(v.z); b.w = f2b(v.w);
    Xb4[g] = b;
    float ss = v.x * v.x + v.y * v.y + v.z * v.z + v.w * v.w;
    ss += __shfl_xor(ss, 8, 16);
    ss += __shfl_xor(ss, 4, 16);
    ss += __shfl_xor(ss, 2, 16);
    ss += __shfl_xor(ss, 1, 16);
    if ((tid & 15) == 0) sq[g >> 4] = ss;
    // column partial sums: col group c4 = tid&15 (cols 4*c4..4*c4+3), rowgrp = tid>>4
    sm[tid] = v;
    __syncthreads();
#pragma unroll
    for (int off = 128; off >= 16; off >>= 1) {
        if (tid < off) {
            float4 o = sm[tid + off];
            float4 m = sm[tid];
            m.x += o.x; m.y += o.y; m.z += o.z; m.w += o.w;
            sm[tid] = m;
        }
        __syncthreads();
    }
    if (tid < 16) Vp4[blockIdx.x * 16 + tid] = sm[tid];   // [512][64] floats
}

// Kernel 2: S = sum(sq); V[c] = sum of Vp partials; mean = 2S/N - 2||V||^2/N^2;
// scal = 1/(2*ALPHA*mean). One block.
__global__ __launch_bounds__(256) void gk_finalize(const float* __restrict__ sq,
                                                   const float* __restrict__ Vp,
                                                   float* __restrict__ scal) {
    __shared__ float red[256];
    const int tid = threadIdx.x;
    float s = 0.f;
    for (int r = tid; r < N; r += 256) s += sq[r];
    red[tid] = s;
    __syncthreads();
    for (int off = 128; off > 0; off >>= 1) {
        if (tid < off) red[tid] += red[tid + off];
        __syncthreads();
    }
    const float S = red[0];
    __syncthreads();
    // V[c]: 512 partials per column, 4 threads per column
    const int c = tid & 63, p = tid >> 6;
    float v = 0.f;
    for (int r = p; r < 512; r += 4) v += Vp[r * 64 + c];
    red[tid] = v;
    __syncthreads();
    if (tid < 128) red[tid] += red[tid + 128];
    __syncthreads();
    if (tid < 64) red[tid] += red[tid + 64];
    __syncthreads();
    float vv = (tid < 64) ? red[tid] * red[tid] : 0.f;
    __syncthreads();
    red[tid] = vv;
    __syncthreads();
    for (int off = 128; off > 0; off >>= 1) {
        if (tid < off) red[tid] += red[tid + off];
        __syncthreads();
    }
    if (tid == 0) {
        const float Vsq = red[0];
        const float fN = (float)N;
        const float mean = 2.f * S / fN - 2.f * Vsq / (fN * fN);
        scal[0] = 1.f / (2.f * mean);   // ALPHA = 1.0
    }
}

// Kernel 3: main GEMM+epilogue. Block tile 64 rows x 128 cols; 4 waves x (16r x 128c).
// TRANSPOSED mfma (swap A/B): pass A = X rows of the COLUMN block, B = X rows of the
// ROW block. Then D[dr][dc] = G(i0+dc, j0+16t+dr), so per lane:
//   out row = i0 + (lane&15)            (FIXED per lane)
//   out col = j0 + 16t + 4*(lane>>4)+r  (reg-consecutive -> f32x4 store)
// 8 nontemporal dwordx4 stores/lane replace 32 scalar dword stores.
__global__ __launch_bounds__(256) void gk_main(const unsigned short* __restrict__ Xb,
                                               const float* __restrict__ sq,
                                               const float* __restrict__ scal,
                                               float* __restrict__ out) {
    const int lane = threadIdx.x & 63;
    const int wave = threadIdx.x >> 6;
    const int i0 = blockIdx.y * 64 + wave * 16;   // row tile (16 rows per wave)
    const int j0 = blockIdx.x * 128;              // col tile (x fast => contiguous writes)
    const int m = lane & 15;
    const int q = lane >> 4;   // 0..3
    const float c0 = scal[0];

    // B fragment: rows of the ROW block. Lane l: row i0+m, k = 8q..8q+7 (+32).
    const bf16x8* Brow = reinterpret_cast<const bf16x8*>(Xb + (i0 + m) * D + 8 * q);
    const bf16x8 b0 = Brow[0];   // k in [8q, 8q+8)
    const bf16x8 b1 = Brow[4];   // k in [32+8q, ...)

    f32x4 acc[8];
#pragma unroll
    for (int t = 0; t < 8; ++t) acc[t] = (f32x4){0.f, 0.f, 0.f, 0.f};

#pragma unroll
    for (int t = 0; t < 8; ++t) {
        // A fragment: rows of the COLUMN block (j-rows), same load shape
        const bf16x8* Arow =
            reinterpret_cast<const bf16x8*>(Xb + (j0 + t * 16 + m) * D + 8 * q);
        acc[t] = __builtin_amdgcn_mfma_f32_16x16x32_bf16(Arow[0], b0, acc[t], 0, 0, 0);
        acc[t] = __builtin_amdgcn_mfma_f32_16x16x32_bf16(Arow[4], b1, acc[t], 0, 0, 0);
    }

    const float sqi = sq[i0 + m];                               // fixed row -> scalar
    float* orow = out + (size_t)(i0 + m) * N + j0 + 4 * q;      // row base for this lane
    const f32x4* sq4 = reinterpret_cast<const f32x4*>(sq + j0 + 4 * q);

#pragma unroll
    for (int t = 0; t < 8; ++t) {
        const f32x4 sj = sq4[t * 4];   // sq[j0 + 16t + 4q .. +3]
        f32x4 e;
        e[0] = __expf(-fmaxf(sqi + sj[0] - 2.f * acc[t][0], 0.f) * c0);
        e[1] = __expf(-fmaxf(sqi + sj[1] - 2.f * acc[t][1], 0.f) * c0);
        e[2] = __expf(-fmaxf(sqi + sj[2] - 2.f * acc[t][2], 0.f) * c0);
        e[3] = __expf(-fmaxf(sqi + sj[3] - 2.f * acc[t][3], 0.f) * c0);
        __builtin_nontemporal_store(e, reinterpret_cast<f32x4*>(orow + t * 16));
    }
}

extern "C" void kernel_launch(void* const* d_in, const int* in_sizes, int n_in,
                              void* d_out, int out_size, void* d_ws, size_t ws_size,
                              hipStream_t stream) {
    const float* X = (const float*)d_in[0];
    float* out = (float*)d_out;

    char* ws = (char*)d_ws;
    unsigned short* Xb = (unsigned short*)ws;                      // 1 MiB
    float* sq = (float*)(ws + (1 << 20));                          // 32 KiB
    float* Vp = (float*)(ws + (1 << 20) + (32 << 10));             // 128 KiB
    float* scal = (float*)(ws + (1 << 20) + (32 << 10) + (128 << 10));

    gk_prep<<<512, 256, 0, stream>>>((const float4*)X, (ushort4*)Xb, sq, (float4*)Vp);
    gk_finalize<<<1, 256, 0, stream>>>(sq, Vp, scal);

    dim3 grid(N / 128, N / 64);   // x = 64 col tiles (fast), y = 128 row tiles
    gk_main<<<grid, 256, 0, stream>>>(Xb, sq, scal, out);
}

// Round 3
// 342.544 us; speedup vs baseline: 1.0250x; 1.0250x over previous
//
#include <hip/hip_runtime.h>
#include <hip/hip_bf16.h>

#define N 8192
#define D 64

typedef __attribute__((ext_vector_type(8))) short bf16x8;
typedef __attribute__((ext_vector_type(4))) float f32x4;

__device__ inline unsigned short f2b(float f) {
    __hip_bfloat16 h = __float2bfloat16(f);
    return __builtin_bit_cast(unsigned short, h);
}

// Kernel 1: X (fp32) -> Xb (bf16); sq[i] = ||x_i||^2; per-block column partials Vp.
// 512 blocks x 256 threads, each thread one float4 (4 elems). 16 threads = 1 row.
__global__ __launch_bounds__(256) void gk_prep(const float4* __restrict__ X4,
                                               ushort4* __restrict__ Xb4,
                                               float* __restrict__ sq,
                                               float4* __restrict__ Vp4) {
    __shared__ float4 sm[256];
    const int tid = threadIdx.x;
    const int g = blockIdx.x * 256 + tid;   // float4 index
    float4 v = X4[g];
    ushort4 b;
    b.x = f2b(v.x); b.y = f2b(v.y); b.z = f2b(v.z); b.w = f2b(v.w);
    Xb4[g] = b;
    float ss = v.x * v.x + v.y * v.y + v.z * v.z + v.w * v.w;
    ss += __shfl_xor(ss, 8, 16);
    ss += __shfl_xor(ss, 4, 16);
    ss += __shfl_xor(ss, 2, 16);
    ss += __shfl_xor(ss, 1, 16);
    if ((tid & 15) == 0) sq[g >> 4] = ss;
    // column partial sums: col group c4 = tid&15 (cols 4*c4..4*c4+3), rowgrp = tid>>4
    sm[tid] = v;
    __syncthreads();
#pragma unroll
    for (int off = 128; off >= 16; off >>= 1) {
        if (tid < off) {
            float4 o = sm[tid + off];
            float4 m = sm[tid];
            m.x += o.x; m.y += o.y; m.z += o.z; m.w += o.w;
            sm[tid] = m;
        }
        __syncthreads();
    }
    if (tid < 16) Vp4[blockIdx.x * 16 + tid] = sm[tid];   // [512][64] floats
}

// Kernel 2: S = sum(sq); V[c] = sum of Vp partials; mean = 2S/N - 2||V||^2/N^2;
// scal = 1/(2*ALPHA*mean). One block.
__global__ __launch_bounds__(256) void gk_finalize(const float* __restrict__ sq,
                                                   const float* __restrict__ Vp,
                                                   float* __restrict__ scal) {
    __shared__ float red[256];
    const int tid = threadIdx.x;
    float s = 0.f;
    for (int r = tid; r < N; r += 256) s += sq[r];
    red[tid] = s;
    __syncthreads();
    for (int off = 128; off > 0; off >>= 1) {
        if (tid < off) red[tid] += red[tid + off];
        __syncthreads();
    }
    const float S = red[0];
    __syncthreads();
    // V[c]: 512 partials per column, 4 threads per column
    const int c = tid & 63, p = tid >> 6;
    float v = 0.f;
    for (int r = p; r < 512; r += 4) v += Vp[r * 64 + c];
    red[tid] = v;
    __syncthreads();
    if (tid < 128) red[tid] += red[tid + 128];
    __syncthreads();
    if (tid < 64) red[tid] += red[tid + 64];
    __syncthreads();
    float vv = (tid < 64) ? red[tid] * red[tid] : 0.f;
    __syncthreads();
    red[tid] = vv;
    __syncthreads();
    for (int off = 128; off > 0; off >>= 1) {
        if (tid < off) red[tid] += red[tid + off];
        __syncthreads();
    }
    if (tid == 0) {
        const float Vsq = red[0];
        const float fN = (float)N;
        const float mean = 2.f * S / fN - 2.f * Vsq / (fN * fN);
        scal[0] = 1.f / (2.f * mean);   // ALPHA = 1.0
    }
}

// Kernel 3: main GEMM+epilogue. Block tile 64 rows x 128 cols; 4 waves x (16r x 128c).
// TRANSPOSED mfma (swap A/B): pass A = X rows of the COLUMN block, B = X rows of the
// ROW block. Then D[dr][dc] = G(i0+dc, j0+16t+dr), so per lane:
//   out row = i0 + (lane&15)            (FIXED per lane)
//   out col = j0 + 16t + 4*(lane>>4)+r  (reg-consecutive -> f32x4 store)
// Plain (write-back) dwordx4 stores: L2 aggregates the two 64B halves of each
// 128B line from adjacent t-iterations. [R1 lesson: nt streamed 64B partials
// past L2 and regressed +36us — do not re-add nt.]
__global__ __launch_bounds__(256) void gk_main(const unsigned short* __restrict__ Xb,
                                               const float* __restrict__ sq,
                                               const float* __restrict__ scal,
                                               float* __restrict__ out) {
    const int lane = threadIdx.x & 63;
    const int wave = threadIdx.x >> 6;
    const int i0 = blockIdx.y * 64 + wave * 16;   // row tile (16 rows per wave)
    const int j0 = blockIdx.x * 128;              // col tile (x fast => contiguous writes)
    const int m = lane & 15;
    const int q = lane >> 4;   // 0..3
    const float c0 = scal[0];

    // B fragment: rows of the ROW block. Lane l: row i0+m, k = 8q..8q+7 (+32).
    const bf16x8* Brow = reinterpret_cast<const bf16x8*>(Xb + (i0 + m) * D + 8 * q);
    const bf16x8 b0 = Brow[0];   // k in [8q, 8q+8)
    const bf16x8 b1 = Brow[4];   // k in [32+8q, ...)

    f32x4 acc[8];
#pragma unroll
    for (int t = 0; t < 8; ++t) acc[t] = (f32x4){0.f, 0.f, 0.f, 0.f};

#pragma unroll
    for (int t = 0; t < 8; ++t) {
        // A fragment: rows of the COLUMN block (j-rows), same load shape
        const bf16x8* Arow =
            reinterpret_cast<const bf16x8*>(Xb + (j0 + t * 16 + m) * D + 8 * q);
        acc[t] = __builtin_amdgcn_mfma_f32_16x16x32_bf16(Arow[0], b0, acc[t], 0, 0, 0);
        acc[t] = __builtin_amdgcn_mfma_f32_16x16x32_bf16(Arow[4], b1, acc[t], 0, 0, 0);
    }

    const float sqi = sq[i0 + m];                               // fixed row -> scalar
    float* orow = out + (size_t)(i0 + m) * N + j0 + 4 * q;      // row base for this lane
    const f32x4* sq4 = reinterpret_cast<const f32x4*>(sq + j0 + 4 * q);

#pragma unroll
    for (int t = 0; t < 8; ++t) {
        const f32x4 sj = sq4[t * 4];   // sq[j0 + 16t + 4q .. +3]
        f32x4 e;
        e[0] = __expf(-fmaxf(sqi + sj[0] - 2.f * acc[t][0], 0.f) * c0);
        e[1] = __expf(-fmaxf(sqi + sj[1] - 2.f * acc[t][1], 0.f) * c0);
        e[2] = __expf(-fmaxf(sqi + sj[2] - 2.f * acc[t][2], 0.f) * c0);
        e[3] = __expf(-fmaxf(sqi + sj[3] - 2.f * acc[t][3], 0.f) * c0);
        *reinterpret_cast<f32x4*>(orow + t * 16) = e;   // write-back dwordx4
    }
}

extern "C" void kernel_launch(void* const* d_in, const int* in_sizes, int n_in,
                              void* d_out, int out_size, void* d_ws, size_t ws_size,
                              hipStream_t stream) {
    const float* X = (const float*)d_in[0];
    float* out = (float*)d_out;

    char* ws = (char*)d_ws;
    unsigned short* Xb = (unsigned short*)ws;                      // 1 MiB
    float* sq = (float*)(ws + (1 << 20));                          // 32 KiB
    float* Vp = (float*)(ws + (1 << 20) + (32 << 10));             // 128 KiB
    float* scal = (float*)(ws + (1 << 20) + (32 << 10) + (128 << 10));

    gk_prep<<<512, 256, 0, stream>>>((const float4*)X, (ushort4*)Xb, sq, (float4*)Vp);
    gk_finalize<<<1, 256, 0, stream>>>(sq, Vp, scal);

    dim3 grid(N / 128, N / 64);   // x = 64 col tiles (fast), y = 128 row tiles
    gk_main<<<grid, 256, 0, stream>>>(Xb, sq, scal, out);
}

// Round 5
// 334.371 us; speedup vs baseline: 1.0500x; 1.0244x over previous
//
#include <hip/hip_runtime.h>
#include <hip/hip_bf16.h>

#define N 8192
#define D 64

typedef __attribute__((ext_vector_type(8))) short bf16x8;
typedef __attribute__((ext_vector_type(4))) float f32x4;

__device__ inline unsigned short f2b(float f) {
    __hip_bfloat16 h = __float2bfloat16(f);
    return __builtin_bit_cast(unsigned short, h);
}

__device__ inline float exp2fast(float x) {
#if __has_builtin(__builtin_amdgcn_exp2f)
    return __builtin_amdgcn_exp2f(x);   // v_exp_f32 (D = 2^S0)
#else
    return exp2f(x);
#endif
}

// Kernel 1: X (fp32) -> Xb (bf16); sq[i] = ||x_i||^2; per-block column partials Vp.
__global__ __launch_bounds__(256) void gk_prep(const float4* __restrict__ X4,
                                               ushort4* __restrict__ Xb4,
                                               float* __restrict__ sq,
                                               float4* __restrict__ Vp4) {
    __shared__ float4 sm[256];
    const int tid = threadIdx.x;
    const int g = blockIdx.x * 256 + tid;   // float4 index
    float4 v = X4[g];
    ushort4 b;
    b.x = f2b(v.x); b.y = f2b(v.y); b.z = f2b(v.z); b.w = f2b(v.w);
    Xb4[g] = b;
    float ss = v.x * v.x + v.y * v.y + v.z * v.z + v.w * v.w;
    ss += __shfl_xor(ss, 8, 16);
    ss += __shfl_xor(ss, 4, 16);
    ss += __shfl_xor(ss, 2, 16);
    ss += __shfl_xor(ss, 1, 16);
    if ((tid & 15) == 0) sq[g >> 4] = ss;
    sm[tid] = v;
    __syncthreads();
#pragma unroll
    for (int off = 128; off >= 16; off >>= 1) {
        if (tid < off) {
            float4 o = sm[tid + off];
            float4 m = sm[tid];
            m.x += o.x; m.y += o.y; m.z += o.z; m.w += o.w;
            sm[tid] = m;
        }
        __syncthreads();
    }
    if (tid < 16) Vp4[blockIdx.x * 16 + tid] = sm[tid];   // [512][64] floats
}

// Kernel 2: S=sum(sq); V[c]=sum Vp; mean = 2S/N - 2||V||^2/N^2; sc = 1/(2*mean).
// Also writes u[i] = sq[i] * sc * log2(e) and scal[1] = 2*sc*log2(e), so the main
// kernel's epilogue is exp2(min(k2*acc - (u_i+u_j), 0)) — positive scale commutes
// with the max(.,0) clamp, so numerics match exp(-max(d2,0)/(2*sigma^2)).
__global__ __launch_bounds__(256) void gk_finalize(const float* __restrict__ sq,
                                                   const float* __restrict__ Vp,
                                                   float* __restrict__ scal,
                                                   float4* __restrict__ u4) {
    __shared__ float red[256];
    const int tid = threadIdx.x;
    float s = 0.f;
    for (int r = tid; r < N; r += 256) s += sq[r];
    red[tid] = s;
    __syncthreads();
    for (int off = 128; off > 0; off >>= 1) {
        if (tid < off) red[tid] += red[tid + off];
        __syncthreads();
    }
    const float S = red[0];
    __syncthreads();
    const int c = tid & 63, p = tid >> 6;
    float v = 0.f;
    for (int r = p; r < 512; r += 4) v += Vp[r * 64 + c];
    red[tid] = v;
    __syncthreads();
    if (tid < 128) red[tid] += red[tid + 128];
    __syncthreads();
    if (tid < 64) red[tid] += red[tid + 64];
    __syncthreads();
    float vv = (tid < 64) ? red[tid] * red[tid] : 0.f;
    __syncthreads();
    red[tid] = vv;
    __syncthreads();
    for (int off = 128; off > 0; off >>= 1) {
        if (tid < off) red[tid] += red[tid + off];
        __syncthreads();
    }
    if (tid == 0) {
        const float Vsq = red[0];
        const float fN = (float)N;
        const float mean = 2.f * S / fN - 2.f * Vsq / (fN * fN);
        const float sc = 1.f / (2.f * mean);          // ALPHA = 1.0
        const float L2E = 1.4426950408889634f;
        scal[0] = sc;
        scal[1] = 2.f * sc * L2E;                     // k2
        red[0] = sc * L2E;                            // broadcast uc
    }
    __syncthreads();
    const float uc = red[0];
    const float4* sqv = reinterpret_cast<const float4*>(sq);
    for (int r = tid; r < N / 4; r += 256) {
        float4 q = sqv[r];
        float4 o;
        o.x = q.x * uc; o.y = q.y * uc; o.z = q.z * uc; o.w = q.w * uc;
        u4[r] = o;
    }
}

// Kernel 3: main GEMM + epilogue. Block 64 rows x 128 cols, 4 waves x (16r x 128c).
// Transposed mfma: lane (q,m) holds row i0+m, cols 16t+4q..+3 (f32x4 regs).
// [R3 lesson] Storing those regs directly = 16 distinct 128B lines per 16-lane
// issue group (rows 32KB apart), 16B partial-line writes -> slower than scalar
// stores. Fix: stage the 16x128 wave tile in LDS (rotate swizzle col+4*row mod 128
// -> free bank pattern on b128 write AND read), read back linearly, store
// fill-shaped: per instr 2 rows x 512B contiguous; per 16-lane group 256B = 2
// FULL lines, zero partial-line writes. Intra-wave only, no barriers.
__global__ __launch_bounds__(256) void gk_main(const unsigned short* __restrict__ Xb,
                                               const float* __restrict__ u,
                                               const float* __restrict__ scal,
                                               float* __restrict__ out) {
    __shared__ float lds[4][16][128];   // 8 KB per wave, 32 KB total
    const int lane = threadIdx.x & 63;
    const int wave = threadIdx.x >> 6;
    const int i0 = blockIdx.y * 64 + wave * 16;   // row tile (16 rows per wave)
    const int j0 = blockIdx.x * 128;              // col tile (x fast)
    const int m = lane & 15;
    const int q = lane >> 4;   // 0..3
    const float k2 = scal[1];

    // B fragment: rows of the ROW block. Lane l: row i0+m, k = 8q..8q+7 (+32).
    const bf16x8* Brow = reinterpret_cast<const bf16x8*>(Xb + (i0 + m) * D + 8 * q);
    const bf16x8 b0 = Brow[0];
    const bf16x8 b1 = Brow[4];

    f32x4 acc[8];
#pragma unroll
    for (int t = 0; t < 8; ++t) acc[t] = (f32x4){0.f, 0.f, 0.f, 0.f};

#pragma unroll
    for (int t = 0; t < 8; ++t) {
        const bf16x8* Arow =
            reinterpret_cast<const bf16x8*>(Xb + (j0 + t * 16 + m) * D + 8 * q);
        acc[t] = __builtin_amdgcn_mfma_f32_16x16x32_bf16(Arow[0], b0, acc[t], 0, 0, 0);
        acc[t] = __builtin_amdgcn_mfma_f32_16x16x32_bf16(Arow[4], b1, acc[t], 0, 0, 0);
    }

    const float ui = u[i0 + m];
    const f32x4* u4 = reinterpret_cast<const f32x4*>(u + j0 + 4 * q);
    float* ldsrow = &lds[wave][m][0];

#pragma unroll
    for (int t = 0; t < 8; ++t) {
        const f32x4 uj = u4[t * 4];     // u[j0 + 16t + 4q .. +3]
        f32x4 e;
#pragma unroll
        for (int r = 0; r < 4; ++r) {
            const float s = ui + uj[r];
            const float pz = fmaf(k2, acc[t][r], -s);   // k2*acc - (ui+uj)  (<=0 side kept)
            e[r] = exp2fast(fminf(pz, 0.f));
        }
        const int cs = (16 * t + 4 * q + 4 * m) & 127;  // rotate by 4*row
        *reinterpret_cast<f32x4*>(ldsrow + cs) = e;     // ds_write_b128
    }

    // Linear read-back + fill-shaped global stores.
    const int half = lane >> 5;          // 0/1 -> row within pair
    const int c = (lane & 31) * 4;       // col of this lane's 16B
#pragma unroll
    for (int p = 0; p < 8; ++p) {
        const int r = 2 * p + half;
        const int cr = (c + 4 * r) & 127;
        const f32x4 v = *reinterpret_cast<const f32x4*>(&lds[wave][r][cr]);
        *reinterpret_cast<f32x4*>(out + (size_t)(i0 + r) * N + j0 + c) = v;
    }
}

extern "C" void kernel_launch(void* const* d_in, const int* in_sizes, int n_in,
                              void* d_out, int out_size, void* d_ws, size_t ws_size,
                              hipStream_t stream) {
    const float* X = (const float*)d_in[0];
    float* out = (float*)d_out;

    char* ws = (char*)d_ws;
    unsigned short* Xb = (unsigned short*)ws;                       // 1 MiB
    float* sq = (float*)(ws + (1 << 20));                           // 32 KiB
    float* Vp = (float*)(ws + (1 << 20) + (32 << 10));              // 128 KiB
    float* u  = (float*)(ws + (1 << 20) + (160 << 10));             // 32 KiB
    float* scal = (float*)(ws + (1 << 20) + (192 << 10));           // scalars

    gk_prep<<<512, 256, 0, stream>>>((const float4*)X, (ushort4*)Xb, sq, (float4*)Vp);
    gk_finalize<<<1, 256, 0, stream>>>(sq, Vp, scal, (float4*)u);

    dim3 grid(N / 128, N / 64);   // x = col tiles (fast), y = row tiles
    gk_main<<<grid, 256, 0, stream>>>(Xb, u, scal, out);
}

// Round 6
// 332.689 us; speedup vs baseline: 1.0553x; 1.0051x over previous
//
#include <hip/hip_runtime.h>
#include <hip/hip_bf16.h>

#define N 8192
#define D 64

typedef __attribute__((ext_vector_type(8))) short bf16x8;
typedef __attribute__((ext_vector_type(4))) float f32x4;

__device__ inline unsigned short f2b(float f) {
    __hip_bfloat16 h = __float2bfloat16(f);
    return __builtin_bit_cast(unsigned short, h);
}

__device__ inline float exp2fast(float x) {
#if __has_builtin(__builtin_amdgcn_exp2f)
    return __builtin_amdgcn_exp2f(x);   // v_exp_f32 (D = 2^S0)
#else
    return exp2f(x);
#endif
}

// Kernel 1: X (fp32) -> Xb (bf16); sq[i] = ||x_i||^2; per-block column partials Vp.
// [kept from R5 — fusion of colsum into prep is correctness-proven and cheap]
__global__ __launch_bounds__(256) void gk_prep(const float4* __restrict__ X4,
                                               ushort4* __restrict__ Xb4,
                                               float* __restrict__ sq,
                                               float4* __restrict__ Vp4) {
    __shared__ float4 sm[256];
    const int tid = threadIdx.x;
    const int g = blockIdx.x * 256 + tid;   // float4 index
    float4 v = X4[g];
    ushort4 b;
    b.x = f2b(v.x); b.y = f2b(v.y); b.z = f2b(v.z); b.w = f2b(v.w);
    Xb4[g] = b;
    float ss = v.x * v.x + v.y * v.y + v.z * v.z + v.w * v.w;
    ss += __shfl_xor(ss, 8, 16);
    ss += __shfl_xor(ss, 4, 16);
    ss += __shfl_xor(ss, 2, 16);
    ss += __shfl_xor(ss, 1, 16);
    if ((tid & 15) == 0) sq[g >> 4] = ss;
    sm[tid] = v;
    __syncthreads();
#pragma unroll
    for (int off = 128; off >= 16; off >>= 1) {
        if (tid < off) {
            float4 o = sm[tid + off];
            float4 m = sm[tid];
            m.x += o.x; m.y += o.y; m.z += o.z; m.w += o.w;
            sm[tid] = m;
        }
        __syncthreads();
    }
    if (tid < 16) Vp4[blockIdx.x * 16 + tid] = sm[tid];   // [512][64] floats
}

// Kernel 2: S=sum(sq); V[c]=sum Vp; mean = 2S/N - 2||V||^2/N^2; sc = 1/(2*mean).
// Writes u[i] = sq[i]*sc*log2(e) and scal[1] = 2*sc*log2(e):
// epilogue becomes exp2(min(k2*acc - (u_i+u_j), 0)) — positive scale commutes with
// the max(.,0) clamp, numerics proven identical (absmax unchanged R3/R5).
__global__ __launch_bounds__(256) void gk_finalize(const float* __restrict__ sq,
                                                   const float* __restrict__ Vp,
                                                   float* __restrict__ scal,
                                                   float4* __restrict__ u4) {
    __shared__ float red[256];
    const int tid = threadIdx.x;
    float s = 0.f;
    for (int r = tid; r < N; r += 256) s += sq[r];
    red[tid] = s;
    __syncthreads();
    for (int off = 128; off > 0; off >>= 1) {
        if (tid < off) red[tid] += red[tid + off];
        __syncthreads();
    }
    const float S = red[0];
    __syncthreads();
    const int c = tid & 63, p = tid >> 6;
    float v = 0.f;
    for (int r = p; r < 512; r += 4) v += Vp[r * 64 + c];
    red[tid] = v;
    __syncthreads();
    if (tid < 128) red[tid] += red[tid + 128];
    __syncthreads();
    if (tid < 64) red[tid] += red[tid + 64];
    __syncthreads();
    float vv = (tid < 64) ? red[tid] * red[tid] : 0.f;
    __syncthreads();
    red[tid] = vv;
    __syncthreads();
    for (int off = 128; off > 0; off >>= 1) {
        if (tid < off) red[tid] += red[tid + off];
        __syncthreads();
    }
    if (tid == 0) {
        const float Vsq = red[0];
        const float fN = (float)N;
        const float mean = 2.f * S / fN - 2.f * Vsq / (fN * fN);
        const float sc = 1.f / (2.f * mean);          // ALPHA = 1.0
        const float L2E = 1.4426950408889634f;
        scal[0] = sc;
        scal[1] = 2.f * sc * L2E;                     // k2
        red[0] = sc * L2E;                            // broadcast uc
    }
    __syncthreads();
    const float uc = red[0];
    const float4* sqv = reinterpret_cast<const float4*>(sq);
    for (int r = tid; r < N / 4; r += 256) {
        float4 q = sqv[r];
        float4 o;
        o.x = q.x * uc; o.y = q.y * uc; o.z = q.z * uc; o.w = q.w * uc;
        u4[r] = o;
    }
}

// Kernel 3: main — EXACT R0 structure (empirical best: ~132us), only the epilogue
// math changed (u[] + exp2 diet; identical memory access shape).
// [R3 lesson] dwordx4 per-lane stores (16 rows/16-lane group) = worse, not better.
// [R5 lesson] LDS-transposed fill-shaped stores also worse (LDS occupancy + tail
// serialization). All store shapes move the same 4.2M 64B sectors; scalar-store
// R0 layout is the empirical winner — do not "improve" the store pattern again.
__global__ __launch_bounds__(256) void gk_main(const unsigned short* __restrict__ Xb,
                                               const float* __restrict__ u,
                                               const float* __restrict__ scal,
                                               float* __restrict__ out) {
    const int lane = threadIdx.x & 63;
    const int wave = threadIdx.x >> 6;
    const int i0 = blockIdx.x * 64 + wave * 16;
    const int j0 = blockIdx.y * 128;
    const int m = lane & 15;
    const int q = lane >> 4;   // 0..3
    const float k2 = scal[1];

    // A fragments: row i0+m, k = 8q..8q+7 (+32 for second chunk)
    const bf16x8* Arow = reinterpret_cast<const bf16x8*>(Xb + (i0 + m) * D + 8 * q);
    const bf16x8 a0 = Arow[0];
    const bf16x8 a1 = Arow[4];

    f32x4 acc[8];
#pragma unroll
    for (int t = 0; t < 8; ++t) acc[t] = (f32x4){0.f, 0.f, 0.f, 0.f};

#pragma unroll
    for (int t = 0; t < 8; ++t) {
        const bf16x8* Brow =
            reinterpret_cast<const bf16x8*>(Xb + (j0 + t * 16 + m) * D + 8 * q);
        const bf16x8 b0 = Brow[0];
        const bf16x8 b1 = Brow[4];
        acc[t] = __builtin_amdgcn_mfma_f32_16x16x32_bf16(a0, b0, acc[t], 0, 0, 0);
        acc[t] = __builtin_amdgcn_mfma_f32_16x16x32_bf16(a1, b1, acc[t], 0, 0, 0);
    }

    float ui[4];
#pragma unroll
    for (int r = 0; r < 4; ++r) ui[r] = u[i0 + 4 * q + r];

#pragma unroll
    for (int t = 0; t < 8; ++t) {
        const int col = j0 + t * 16 + m;
        const float uj = u[col];
#pragma unroll
        for (int r = 0; r < 4; ++r) {
            const float pz = fmaf(k2, acc[t][r], -(ui[r] + uj));
            out[(size_t)(i0 + 4 * q + r) * N + col] = exp2fast(fminf(pz, 0.f));
        }
    }
}

extern "C" void kernel_launch(void* const* d_in, const int* in_sizes, int n_in,
                              void* d_out, int out_size, void* d_ws, size_t ws_size,
                              hipStream_t stream) {
    const float* X = (const float*)d_in[0];
    float* out = (float*)d_out;

    char* ws = (char*)d_ws;
    unsigned short* Xb = (unsigned short*)ws;                       // 1 MiB
    float* sq = (float*)(ws + (1 << 20));                           // 32 KiB
    float* Vp = (float*)(ws + (1 << 20) + (32 << 10));              // 128 KiB
    float* u  = (float*)(ws + (1 << 20) + (160 << 10));             // 32 KiB
    float* scal = (float*)(ws + (1 << 20) + (192 << 10));           // scalars

    gk_prep<<<512, 256, 0, stream>>>((const float4*)X, (ushort4*)Xb, sq, (float4*)Vp);
    gk_finalize<<<1, 256, 0, stream>>>(sq, Vp, scal, (float4*)u);

    dim3 grid(N / 64, N / 128);   // x = row tiles, y = col tiles  (R0 layout)
    gk_main<<<grid, 256, 0, stream>>>(Xb, u, scal, out);
}

// Round 7
// 329.959 us; speedup vs baseline: 1.0641x; 1.0083x over previous
//
#include <hip/hip_runtime.h>
#include <hip/hip_bf16.h>

#define N 8192
#define D 64

typedef __attribute__((ext_vector_type(8))) short bf16x8;
typedef __attribute__((ext_vector_type(4))) float f32x4;

__device__ inline unsigned short f2b(float f) {
    __hip_bfloat16 h = __float2bfloat16(f);
    return __builtin_bit_cast(unsigned short, h);
}

__device__ inline float exp2fast(float x) {
#if __has_builtin(__builtin_amdgcn_exp2f)
    return __builtin_amdgcn_exp2f(x);   // v_exp_f32 (D = 2^S0)
#else
    return exp2f(x);
#endif
}

// Kernel 1: X (fp32) -> Xb (bf16); sq[i] = ||x_i||^2; per-block column partials Vp.
__global__ __launch_bounds__(256) void gk_prep(const float4* __restrict__ X4,
                                               ushort4* __restrict__ Xb4,
                                               float* __restrict__ sq,
                                               float4* __restrict__ Vp4) {
    __shared__ float4 sm[256];
    const int tid = threadIdx.x;
    const int g = blockIdx.x * 256 + tid;   // float4 index
    float4 v = X4[g];
    ushort4 b;
    b.x = f2b(v.x); b.y = f2b(v.y); b.z = f2b(v.z); b.w = f2b(v.w);
    Xb4[g] = b;
    float ss = v.x * v.x + v.y * v.y + v.z * v.z + v.w * v.w;
    ss += __shfl_xor(ss, 8, 16);
    ss += __shfl_xor(ss, 4, 16);
    ss += __shfl_xor(ss, 2, 16);
    ss += __shfl_xor(ss, 1, 16);
    if ((tid & 15) == 0) sq[g >> 4] = ss;
    sm[tid] = v;
    __syncthreads();
#pragma unroll
    for (int off = 128; off >= 16; off >>= 1) {
        if (tid < off) {
            float4 o = sm[tid + off];
            float4 m = sm[tid];
            m.x += o.x; m.y += o.y; m.z += o.z; m.w += o.w;
            sm[tid] = m;
        }
        __syncthreads();
    }
    if (tid < 16) Vp4[blockIdx.x * 16 + tid] = sm[tid];   // [512][64] floats
}

// Kernel 2: S=sum(sq); V[c]=sum Vp; mean = 2S/N - 2||V||^2/N^2; sc = 1/(2*mean).
// u[i] = sq[i]*sc*log2(e), scal[1] = 2*sc*log2(e). Epilogue identity proven
// (absmax bit-identical since R3).
__global__ __launch_bounds__(256) void gk_finalize(const float* __restrict__ sq,
                                                   const float* __restrict__ Vp,
                                                   float* __restrict__ scal,
                                                   float4* __restrict__ u4) {
    __shared__ float red[256];
    const int tid = threadIdx.x;
    float s = 0.f;
    for (int r = tid; r < N; r += 256) s += sq[r];
    red[tid] = s;
    __syncthreads();
    for (int off = 128; off > 0; off >>= 1) {
        if (tid < off) red[tid] += red[tid + off];
        __syncthreads();
    }
    const float S = red[0];
    __syncthreads();
    const int c = tid & 63, p = tid >> 6;
    float v = 0.f;
    for (int r = p; r < 512; r += 4) v += Vp[r * 64 + c];
    red[tid] = v;
    __syncthreads();
    if (tid < 128) red[tid] += red[tid + 128];
    __syncthreads();
    if (tid < 64) red[tid] += red[tid + 64];
    __syncthreads();
    float vv = (tid < 64) ? red[tid] * red[tid] : 0.f;
    __syncthreads();
    red[tid] = vv;
    __syncthreads();
    for (int off = 128; off > 0; off >>= 1) {
        if (tid < off) red[tid] += red[tid + off];
        __syncthreads();
    }
    if (tid == 0) {
        const float Vsq = red[0];
        const float fN = (float)N;
        const float mean = 2.f * S / fN - 2.f * Vsq / (fN * fN);
        const float sc = 1.f / (2.f * mean);          // ALPHA = 1.0
        const float L2E = 1.4426950408889634f;
        scal[0] = sc;
        scal[1] = 2.f * sc * L2E;                     // k2
        red[0] = sc * L2E;                            // broadcast uc
    }
    __syncthreads();
    const float uc = red[0];
    const float4* sqv = reinterpret_cast<const float4*>(sq);
    for (int r = tid; r < N / 4; r += 256) {
        float4 q = sqv[r];
        float4 o;
        o.x = q.x * uc; o.y = q.y * uc; o.z = q.z * uc; o.w = q.w * uc;
        u4[r] = o;
    }
}

// Kernel 3: main — R0 tile/store SHAPE (proven best), restructured SCHEDULE for
// occupancy. [R6 lesson] cross-round noise ±10-15us; all store shapes land in the
// same band while write arithmetic says ~45us -> latency-bound, not shape-bound.
// Fix: each t-tile is an independent 16x16 output (own K=64 accumulation), so run
// {load B, 2 MFMA, epilogue, 4 stores} per t. Live acc = 4 VGPRs (was 32 held
// through whole kernel); unroll 2 caps prefetch depth; store bases precomputed,
// t*256B offsets fit the 13-bit global-store immediate. Target <=84 VGPRs ->
// >=6 waves/SIMD (launch_bounds-enforced) vs ~3 before: 2x TLP for latency hiding.
__global__ __launch_bounds__(256, 6) void gk_main(const unsigned short* __restrict__ Xb,
                                                  const float* __restrict__ u,
                                                  const float* __restrict__ scal,
                                                  float* __restrict__ out) {
    const int lane = threadIdx.x & 63;
    const int wave = threadIdx.x >> 6;
    const int i0 = blockIdx.x * 64 + wave * 16;
    const int j0 = blockIdx.y * 128;
    const int m = lane & 15;
    const int q = lane >> 4;   // 0..3
    const float k2 = scal[1];

    // A fragments: row i0+m, k = 8q..8q+7 (+32 for second chunk)
    const bf16x8* Arow = reinterpret_cast<const bf16x8*>(Xb + (i0 + m) * D + 8 * q);
    const bf16x8 a0 = Arow[0];
    const bf16x8 a1 = Arow[4];

    float ui[4];
#pragma unroll
    for (int r = 0; r < 4; ++r) ui[r] = u[i0 + 4 * q + r];

    // Precomputed bases: B rows at (j0+m)*D + 8q, step t*16 rows = t*128 bf16x8... 
    // (indexed in bf16x8 units: 8 per row); u col base; 4 store row-bases.
    const bf16x8* Bbase = reinterpret_cast<const bf16x8*>(Xb + (j0 + m) * D + 8 * q);
    const float* ucol = u + j0 + m;
    float* ob0 = out + (size_t)(i0 + 4 * q + 0) * N + j0 + m;
    float* ob1 = out + (size_t)(i0 + 4 * q + 1) * N + j0 + m;
    float* ob2 = out + (size_t)(i0 + 4 * q + 2) * N + j0 + m;
    float* ob3 = out + (size_t)(i0 + 4 * q + 3) * N + j0 + m;

#pragma unroll 2
    for (int t = 0; t < 8; ++t) {
        const bf16x8 b0 = Bbase[t * 16 * (D / 8)];       // +t*2048 bytes
        const bf16x8 b1 = Bbase[t * 16 * (D / 8) + 4];   // +32 elems (k-chunk 1)
        f32x4 acc = (f32x4){0.f, 0.f, 0.f, 0.f};
        acc = __builtin_amdgcn_mfma_f32_16x16x32_bf16(a0, b0, acc, 0, 0, 0);
        acc = __builtin_amdgcn_mfma_f32_16x16x32_bf16(a1, b1, acc, 0, 0, 0);
        const float uj = ucol[t * 16];
        const float p0 = fmaf(k2, acc[0], -(ui[0] + uj));
        const float p1 = fmaf(k2, acc[1], -(ui[1] + uj));
        const float p2 = fmaf(k2, acc[2], -(ui[2] + uj));
        const float p3 = fmaf(k2, acc[3], -(ui[3] + uj));
        ob0[t * 16] = exp2fast(fminf(p0, 0.f));   // scalar dword stores: R0's
        ob1[t * 16] = exp2fast(fminf(p1, 0.f));   // proven-best shape (64B/16-lane
        ob2[t * 16] = exp2fast(fminf(p2, 0.f));   // group), offsets are imm.
        ob3[t * 16] = exp2fast(fminf(p3, 0.f));
    }
}

extern "C" void kernel_launch(void* const* d_in, const int* in_sizes, int n_in,
                              void* d_out, int out_size, void* d_ws, size_t ws_size,
                              hipStream_t stream) {
    const float* X = (const float*)d_in[0];
    float* out = (float*)d_out;

    char* ws = (char*)d_ws;
    unsigned short* Xb = (unsigned short*)ws;                       // 1 MiB
    float* sq = (float*)(ws + (1 << 20));                           // 32 KiB
    float* Vp = (float*)(ws + (1 << 20) + (32 << 10));              // 128 KiB
    float* u  = (float*)(ws + (1 << 20) + (160 << 10));             // 32 KiB
    float* scal = (float*)(ws + (1 << 20) + (192 << 10));           // scalars

    gk_prep<<<512, 256, 0, stream>>>((const float4*)X, (ushort4*)Xb, sq, (float4*)Vp);
    gk_finalize<<<1, 256, 0, stream>>>(sq, Vp, scal, (float4*)u);

    dim3 grid(N / 64, N / 128);   // x = row tiles, y = col tiles  (R0 layout)
    gk_main<<<grid, 256, 0, stream>>>(Xb, u, scal, out);
}